// Round 8
// baseline (80.038 us; speedup 1.0000x reference)
//
#include <hip/hip_runtime.h>

// RetinaNet target encoder for MI355X — round 8: wave-private everything.
// Inputs: bboxes [N,4] f32 xyxy, labels [N] i32, priors [M,4] f32 cxcywh.
// Outputs (concat): reg_targets [M,4] f32, cls_targets [M] (written as f32).
//
// N = 1024, M = 49104. Grid (192, 16): block = 256 priors x 64 GTs, but ALL
// work is per-wave (64 priors): wave bbox -> ballot mask of overlapping GTs
// (SGPR, ascending-j extraction via ffs) -> batches of 8 active rows:
//   phase 1: IoU per lane -> per-prior argmax regs + wave-private LDS tile
//   phase 2: 8-lane groups scan one row each, shfl merge (max iou, min m),
//            atomicMax -> partG[gt]  (packed u64)
// NO __syncthreads anywhere (same-wave LDS RAW ordered by lgkmcnt).
//
// Exactness: skipped GT => GT box disjoint from the UNION bbox of the wave's
// 64 prior boxes => every pair intersection is empty => clamped w or h == 0
// => iou == 0.0f bit-exactly in the reference. Strict-> argmax over ascending
// index == numpy first-max; packed u64 (iou_bits<<32)|(~m) max == (max iou,
// smallest m); force-assign duplicates: atomicMax(n) == numpy last-write.
// Padding rows repeat the first active row: equal values never displace a
// strict-> argmax; duplicate phase-2 atomics write identical packed values.
// partG stays 0 only for GTs that some wave never saw... every GT overlaps a
// level-7 prior box (>=512px boxes, centers 64..448 cover the image) with
// iou > 0, so every partG entry gets a positive write. memset-0 is safe.

static constexpr float NEG_THRESH = 0.4f;
static constexpr float POS_THRESH = 0.5f;
static constexpr int N_GT = 1024;
static constexpr int GT_PER_BLK = 64;
static constexpr int NCHUNK = N_GT / GT_PER_BLK;   // 16
static constexpr int MPAD = 49152;                 // M rounded up to 256
static constexpr int BLK = 256;                    // priors per block (4 waves)
static constexpr int NB = MPAD / BLK;              // 192 prior blocks
static constexpr int ROWS = 8;                     // tile rows per batch
static constexpr int RSTRIDE = 72;                 // (g*72+c)%32 spreads groups
                                                   // across banks: 2-way = free

__device__ __forceinline__ float iou_ab(float ax1, float ay1, float ax2, float ay2,
                                        float area_a,
                                        float bx1, float by1, float bx2, float by2,
                                        float area_b) {
#pragma clang fp contract(off)
    float ltx = fmaxf(ax1, bx1);
    float lty = fmaxf(ay1, by1);
    float rbx = fminf(ax2, bx2);
    float rby = fminf(ay2, by2);
    float w = rbx - ltx; if (w < 0.0f) w = 0.0f;
    float h = rby - lty; if (h < 0.0f) h = 0.0f;
    float inter = w * h;
    return inter / (area_a + area_b - inter);
}

// ---------------- Fused kernel ----------------
__global__ void __launch_bounds__(256) fused_kernel(
        const float* __restrict__ bboxes,
        const float* __restrict__ priors,
        float* __restrict__ part1iou,             // [NCHUNK][MPAD]
        unsigned short* __restrict__ part1idx,    // [NCHUNK][MPAD]
        unsigned long long* __restrict__ partG,   // [N_GT], pre-zeroed, atomicMax
        int* __restrict__ force_n,                // [M], init -1 (chunk 0)
        int M) {
#pragma clang fp contract(off)
    __shared__ float tile[4][ROWS][RSTRIDE];      // 9216 B, wave-private slabs

    int tid = threadIdx.x;
    int lane = tid & 63;
    int wid = tid >> 6;
    int bx = blockIdx.x;
    int n0 = blockIdx.y * GT_PER_BLK;
    int m = bx * BLK + tid;
    bool valid = (m < M);

    float4 p = valid ? reinterpret_cast<const float4*>(priors)[m]
                     : make_float4(0.f, 0.f, 0.f, 0.f);
    float bx1 = p.x - p.z / 2.0f;
    float by1 = p.y - p.w / 2.0f;
    float bx2 = p.x + p.z / 2.0f;
    float by2 = p.y + p.w / 2.0f;
    float area_b = (bx2 - bx1) * (by2 - by1);

    // ---- wave bbox over its 64 priors (butterfly; all lanes get result) ----
    float mnx = valid ? bx1 : 1e30f;
    float mny = valid ? by1 : 1e30f;
    float mxx = valid ? bx2 : -1e30f;
    float mxy = valid ? by2 : -1e30f;
#pragma unroll
    for (int mk = 1; mk < 64; mk <<= 1) {
        mnx = fminf(mnx, __shfl_xor(mnx, mk));
        mny = fminf(mny, __shfl_xor(mny, mk));
        mxx = fmaxf(mxx, __shfl_xor(mxx, mk));
        mxy = fmaxf(mxy, __shfl_xor(mxy, mk));
    }

    // ---- test the 64 GTs of this chunk: lane <-> GT, ballot -> SGPR mask ----
    float4 gt = reinterpret_cast<const float4*>(bboxes)[n0 + lane];
    bool hit = (gt.x < mxx) & (gt.z > mnx) & (gt.y < mxy) & (gt.w > mny);
    unsigned long long rem = __ballot(hit);
    int cnt = __popcll(rem);

    float best = 0.0f;    // iou >= 0 everywhere; all-zero -> argmax = chunk's
    int bestjr = n0;      // first GT (encode's ascending-chunk reduce -> 0)

    if (cnt > 0) {
        int j0 = __ffsll(rem) - 1;     // first active row (for padding)
        int grp = lane >> 3;
        int sub = lane & 7;
        int nbatches = (cnt + ROWS - 1) / ROWS;

        for (int b = 0; b < nbatches; ++b) {
            int myj = j0;   // row index this lane's group consumes in phase 2
#pragma unroll
            for (int r = 0; r < ROWS; ++r) {
                int jl;
                if (rem) { jl = __ffsll(rem) - 1; rem &= rem - 1ull; }
                else     { jl = j0; }               // padding row (duplicate)
                jl = __builtin_amdgcn_readfirstlane(jl);

                float4 g = reinterpret_cast<const float4*>(bboxes)[n0 + jl];
                float ga = (g.z - g.x) * (g.w - g.y);
                float iou = iou_ab(g.x, g.y, g.z, g.w, ga,
                                   bx1, by1, bx2, by2, area_b);
                // per-prior argmax: strict > over ascending jl (mask order);
                // padding repeats an earlier value -> never displaces.
                if (iou > best) { best = iou; bestjr = n0 + jl; }
                tile[wid][r][lane] = valid ? iou : -1.0f;
                if (grp == r) myj = jl;
            }

            // ---- phase 2: group g scans row g (same wave, no barrier) ----
            float bi = -2.0f;
            int bm = 0;
#pragma unroll
            for (int k = 0; k < 8; ++k) {
                int c = sub + 8 * k;                // ascending c per lane
                float v = tile[wid][grp][c];
                if (v > bi) { bi = v; bm = c; }     // strict >: smallest c
            }
#pragma unroll
            for (int msk = 1; msk < 8; msk <<= 1) { // stays in 8-lane group
                float oi = __shfl_xor(bi, msk);
                int om = __shfl_xor(bm, msk);
                if (oi > bi || (oi == bi && om < bm)) { bi = oi; bm = om; }
            }
            if (sub == 0 && bi > 0.0f) {
                unsigned wm = (unsigned)(bx * BLK + wid * 64 + bm);
                atomicMax(&partG[n0 + myj],
                          ((unsigned long long)__float_as_uint(bi) << 32) |
                          (unsigned long long)(0xFFFFFFFFu - wm));
            }
        }
    }

    if (valid) {
        size_t row = (size_t)blockIdx.y * MPAD + m;
        part1iou[row] = best;
        part1idx[row] = (unsigned short)bestjr;
        if (blockIdx.y == 0) force_n[m] = -1;   // replay-safe init for rs
    }
}

// ---------------- RS: per-GT winner -> forced-assignment scatter -------------
__global__ void rs_kernel(const unsigned long long* __restrict__ partG,
                          int* __restrict__ force_n) {
    int n = blockIdx.x * blockDim.x + threadIdx.x;
    if (n >= N_GT) return;
    unsigned long long v = partG[n];
    int m = (int)(0xFFFFFFFFu - (unsigned)(v & 0xFFFFFFFFull));
    atomicMax(&force_n[m], n);   // duplicate priors: last write in np == max n
}

// ---------------- E: reduce per-prior partials + encode ----------------------
__global__ void __launch_bounds__(256) encode_kernel(
        const float* __restrict__ bboxes,
        const int* __restrict__ labels,
        const float* __restrict__ priors,
        const float* __restrict__ part1iou,
        const unsigned short* __restrict__ part1idx,
        const int* __restrict__ force_n,
        float* __restrict__ out, int M) {
#pragma clang fp contract(off)
    int m = blockIdx.x * 256 + threadIdx.x;
    if (m >= M) return;

    float bi = part1iou[m];
    int bn = part1idx[m];
    for (int c = 1; c < NCHUNK; ++c) {
        float v = part1iou[(size_t)c * MPAD + m];
        if (v > bi) { bi = v; bn = part1idx[(size_t)c * MPAD + m]; }
    }   // strict > ascending c == smallest n on ties (numpy first-max)

    float iou = bi;
    int mid = bn;
    int f = force_n[m];
    if (f >= 0) { mid = f; iou = POS_THRESH; }

    float4 g = reinterpret_cast<const float4*>(bboxes)[mid];
    float mcx = (g.x + g.z) / 2.0f;
    float mcy = (g.y + g.w) / 2.0f;
    float mw = g.z - g.x;
    float mh = g.w - g.y;

    float4 p = reinterpret_cast<const float4*>(priors)[m];
    float dcx = ((mcx - p.x) / p.z) / 0.1f;
    float dcy = ((mcy - p.y) / p.w) / 0.1f;
    float dw = logf(mw / p.z) / 0.2f;
    float dh = logf(mh / p.w) / 0.2f;

    reinterpret_cast<float4*>(out)[m] = make_float4(dcx, dcy, dw, dh);

    int cls = labels[mid];
    if (iou < POS_THRESH) cls = -1;
    if (iou < NEG_THRESH) cls = 0;
    out[(size_t)4 * M + m] = (float)cls;
}

extern "C" void kernel_launch(void* const* d_in, const int* in_sizes, int n_in,
                              void* d_out, int out_size, void* d_ws, size_t ws_size,
                              hipStream_t stream) {
    const float* bboxes = (const float*)d_in[0];
    const int* labels = (const int*)d_in[1];
    const float* priors = (const float*)d_in[2];
    int M = in_sizes[2] / 4;
    float* out = (float*)d_out;

    // Workspace (~4.9 MB): part1iou | part1idx | partG | force_n
    char* ws = (char*)d_ws;
    float* part1iou = (float*)ws;                                   // 3.15 MB
    unsigned short* part1idx =
        (unsigned short*)(ws + (size_t)NCHUNK * MPAD * 4);          // 1.57 MB
    unsigned long long* partG =
        (unsigned long long*)(ws + (size_t)NCHUNK * MPAD * 6);      // 8 KB
    int* force_n =
        (int*)(ws + (size_t)NCHUNK * MPAD * 6 + (size_t)N_GT * 8);  // 192 KB

    // partG must be 0 each call (atomicMax accumulator; replay-safe)
    hipMemsetAsync(partG, 0, (size_t)N_GT * 8, stream);

    fused_kernel<<<dim3(NB, NCHUNK), 256, 0, stream>>>(bboxes, priors, part1iou,
                                                       part1idx, partG, force_n, M);
    rs_kernel<<<(N_GT + 255) / 256, 256, 0, stream>>>(partG, force_n);
    encode_kernel<<<(MPAD + 255) / 256, 256, 0, stream>>>(bboxes, labels, priors,
                                                          part1iou, part1idx,
                                                          force_n, out, M);
}

// Round 9
// 78.521 us; speedup vs baseline: 1.0193x; 1.0193x over previous
//
#include <hip/hip_runtime.h>

// RetinaNet target encoder for MI355X — round 9: wave-private compaction with
// REGISTER-BROADCAST GT boxes (v_readlane) — no memory ops in the inner loop.
// Inputs: bboxes [N,4] f32 xyxy, labels [N] i32, priors [M,4] f32 cxcywh.
// Outputs (concat): reg_targets [M,4] f32, cls_targets [M] (written as f32).
//
// N = 1024, M = 49104. Grid (192, 16): block = 256 priors x 64 GTs; all work
// per-wave (64 priors):
//   - wave bbox (butterfly) -> ballot mask of overlapping GTs (SGPR)
//   - each lane holds GT[lane]'s box in 5 VGPRs (one coalesced load)
//   - per active row: jl = scalar ffs walk; GT box broadcast from lane jl via
//     v_readlane (no loads, no lgkmcnt); IoU -> per-prior argmax regs +
//     wave-private LDS tile row
//   - per 8-row batch: 8-lane groups scan one tile row each, shfl merge
//     (max iou, min m), atomicMax -> partG[gt]
// NO __syncthreads (same-wave LDS RAW ordered by lgkmcnt).
//
// Exactness (same as round 8): skipped GT => disjoint from the UNION bbox of
// the wave's priors => every pair IoU is bit-exactly 0.0f in the reference.
// Mask walk is ascending j; strict-> argmax == numpy first-max. Packed u64
// (iou_bits<<32)|(~m) max == (max iou, smallest m). Padding rows repeat the
// first active row: equal values never displace strict->; duplicate atomics
// write identical values. Every GT overlaps some level-7 prior with iou > 0,
// so partG zero-init can never be a final winner. Forced-assign duplicates:
// atomicMax(n) == numpy last-write-wins.

static constexpr float NEG_THRESH = 0.4f;
static constexpr float POS_THRESH = 0.5f;
static constexpr int N_GT = 1024;
static constexpr int GT_PER_BLK = 64;
static constexpr int NCHUNK = N_GT / GT_PER_BLK;   // 16
static constexpr int MPAD = 49152;                 // M rounded up to 256
static constexpr int BLK = 256;                    // priors per block (4 waves)
static constexpr int NB = MPAD / BLK;              // 192 prior blocks
static constexpr int ROWS = 8;                     // tile rows per batch
static constexpr int RSTRIDE = 72;                 // 2-way banks max (free)

__device__ __forceinline__ float rdlane(float v, int sl) {
    return __uint_as_float(
        (unsigned)__builtin_amdgcn_readlane((int)__float_as_uint(v), sl));
}

// ---------------- Fused kernel ----------------
__global__ void __launch_bounds__(256) fused_kernel(
        const float* __restrict__ bboxes,
        const float* __restrict__ priors,
        float* __restrict__ part1iou,             // [NCHUNK][MPAD]
        unsigned short* __restrict__ part1idx,    // [NCHUNK][MPAD]
        unsigned long long* __restrict__ partG,   // [N_GT], pre-zeroed, atomicMax
        int* __restrict__ force_n,                // [M], init -1 (chunk 0)
        int M) {
#pragma clang fp contract(off)
    __shared__ float tile[4][ROWS][RSTRIDE];      // 9216 B, wave-private slabs

    int tid = threadIdx.x;
    int lane = tid & 63;
    int wid = tid >> 6;
    int bx = blockIdx.x;
    int n0 = blockIdx.y * GT_PER_BLK;
    int m = bx * BLK + tid;
    bool valid = (m < M);

    float4 p = valid ? reinterpret_cast<const float4*>(priors)[m]
                     : make_float4(0.f, 0.f, 0.f, 0.f);
    float bx1 = p.x - p.z / 2.0f;
    float by1 = p.y - p.w / 2.0f;
    float bx2 = p.x + p.z / 2.0f;
    float by2 = p.y + p.w / 2.0f;
    float area_b = (bx2 - bx1) * (by2 - by1);

    // ---- wave bbox over its 64 priors ----
    float mnx = valid ? bx1 : 1e30f;
    float mny = valid ? by1 : 1e30f;
    float mxx = valid ? bx2 : -1e30f;
    float mxy = valid ? by2 : -1e30f;
#pragma unroll
    for (int mk = 1; mk < 64; mk <<= 1) {
        mnx = fminf(mnx, __shfl_xor(mnx, mk));
        mny = fminf(mny, __shfl_xor(mny, mk));
        mxx = fmaxf(mxx, __shfl_xor(mxx, mk));
        mxy = fmaxf(mxy, __shfl_xor(mxy, mk));
    }

    // ---- lane <-> GT: load chunk's GT boxes into registers, test, ballot ----
    float4 gt = reinterpret_cast<const float4*>(bboxes)[n0 + lane];
    float garea = (gt.z - gt.x) * (gt.w - gt.y);
    bool hit = (gt.x < mxx) & (gt.z > mnx) & (gt.y < mxy) & (gt.w > mny);
    unsigned long long rem = __ballot(hit);
    int cnt = __popcll(rem);

    float best = 0.0f;    // iou >= 0 everywhere; all-zero chunk -> (0, n0)
    int bestjr = n0;

    if (cnt > 0) {
        int j0 = __ffsll(rem) - 1;     // first active row (padding source)
        int grp = lane >> 3;
        int sub = lane & 7;
        int nbatches = (cnt + ROWS - 1) / ROWS;

        for (int b = 0; b < nbatches; ++b) {
            int myj = j0;   // real GT row this lane's group consumes in phase 2
#pragma unroll
            for (int r = 0; r < ROWS; ++r) {
                int jl;
                if (rem) { jl = __ffsll(rem) - 1; rem &= rem - 1ull; }
                else     { jl = j0; }               // padding (duplicate row)

                // Broadcast GT box from lane jl — pure register traffic.
                float gx1 = rdlane(gt.x, jl);
                float gy1 = rdlane(gt.y, jl);
                float gx2 = rdlane(gt.z, jl);
                float gy2 = rdlane(gt.w, jl);
                float ga  = rdlane(garea, jl);

                float ltx = fmaxf(gx1, bx1);
                float lty = fmaxf(gy1, by1);
                float rbx = fminf(gx2, bx2);
                float rby = fminf(gy2, by2);
                float w = rbx - ltx; if (w < 0.0f) w = 0.0f;
                float h = rby - lty; if (h < 0.0f) h = 0.0f;
                float inter = w * h;
                float iou = inter / (ga + area_b - inter);

                // per-prior argmax: strict > over ascending jl (mask order);
                // padding repeats an earlier value -> never displaces.
                if (iou > best) { best = iou; bestjr = n0 + jl; }
                tile[wid][r][lane] = valid ? iou : -1.0f;
                if (grp == r) myj = jl;
            }

            // ---- phase 2: group g scans row g (same wave, no barrier) ----
            float bi = -2.0f;
            int bm = 0;
#pragma unroll
            for (int k = 0; k < 8; ++k) {
                int c = sub + 8 * k;                // ascending c per lane
                float v = tile[wid][grp][c];
                if (v > bi) { bi = v; bm = c; }     // strict >: smallest c
            }
#pragma unroll
            for (int msk = 1; msk < 8; msk <<= 1) { // stays in 8-lane group
                float oi = __shfl_xor(bi, msk);
                int om = __shfl_xor(bm, msk);
                if (oi > bi || (oi == bi && om < bm)) { bi = oi; bm = om; }
            }
            if (sub == 0 && bi > 0.0f) {
                unsigned wm = (unsigned)(bx * BLK + wid * 64 + bm);
                atomicMax(&partG[n0 + myj],
                          ((unsigned long long)__float_as_uint(bi) << 32) |
                          (unsigned long long)(0xFFFFFFFFu - wm));
            }
        }
    }

    if (valid) {
        size_t row = (size_t)blockIdx.y * MPAD + m;
        part1iou[row] = best;
        part1idx[row] = (unsigned short)bestjr;
        if (blockIdx.y == 0) force_n[m] = -1;   // replay-safe init for rs
    }
}

// ---------------- RS: per-GT winner -> forced-assignment scatter -------------
__global__ void rs_kernel(const unsigned long long* __restrict__ partG,
                          int* __restrict__ force_n) {
    int n = blockIdx.x * blockDim.x + threadIdx.x;
    if (n >= N_GT) return;
    unsigned long long v = partG[n];
    int m = (int)(0xFFFFFFFFu - (unsigned)(v & 0xFFFFFFFFull));
    atomicMax(&force_n[m], n);   // duplicate priors: last write in np == max n
}

// ---------------- E: reduce per-prior partials + encode ----------------------
__global__ void __launch_bounds__(256) encode_kernel(
        const float* __restrict__ bboxes,
        const int* __restrict__ labels,
        const float* __restrict__ priors,
        const float* __restrict__ part1iou,
        const unsigned short* __restrict__ part1idx,
        const int* __restrict__ force_n,
        float* __restrict__ out, int M) {
#pragma clang fp contract(off)
    int m = blockIdx.x * 256 + threadIdx.x;
    if (m >= M) return;

    float bi = part1iou[m];
    int bn = part1idx[m];
    for (int c = 1; c < NCHUNK; ++c) {
        float v = part1iou[(size_t)c * MPAD + m];
        if (v > bi) { bi = v; bn = part1idx[(size_t)c * MPAD + m]; }
    }   // strict > ascending c == smallest n on ties (numpy first-max)

    float iou = bi;
    int mid = bn;
    int f = force_n[m];
    if (f >= 0) { mid = f; iou = POS_THRESH; }

    float4 g = reinterpret_cast<const float4*>(bboxes)[mid];
    float mcx = (g.x + g.z) / 2.0f;
    float mcy = (g.y + g.w) / 2.0f;
    float mw = g.z - g.x;
    float mh = g.w - g.y;

    float4 p = reinterpret_cast<const float4*>(priors)[m];
    float dcx = ((mcx - p.x) / p.z) / 0.1f;
    float dcy = ((mcy - p.y) / p.w) / 0.1f;
    float dw = logf(mw / p.z) / 0.2f;
    float dh = logf(mh / p.w) / 0.2f;

    reinterpret_cast<float4*>(out)[m] = make_float4(dcx, dcy, dw, dh);

    int cls = labels[mid];
    if (iou < POS_THRESH) cls = -1;
    if (iou < NEG_THRESH) cls = 0;
    out[(size_t)4 * M + m] = (float)cls;
}

extern "C" void kernel_launch(void* const* d_in, const int* in_sizes, int n_in,
                              void* d_out, int out_size, void* d_ws, size_t ws_size,
                              hipStream_t stream) {
    const float* bboxes = (const float*)d_in[0];
    const int* labels = (const int*)d_in[1];
    const float* priors = (const float*)d_in[2];
    int M = in_sizes[2] / 4;
    float* out = (float*)d_out;

    // Workspace (~4.9 MB): part1iou | part1idx | partG | force_n
    char* ws = (char*)d_ws;
    float* part1iou = (float*)ws;                                   // 3.15 MB
    unsigned short* part1idx =
        (unsigned short*)(ws + (size_t)NCHUNK * MPAD * 4);          // 1.57 MB
    unsigned long long* partG =
        (unsigned long long*)(ws + (size_t)NCHUNK * MPAD * 6);      // 8 KB
    int* force_n =
        (int*)(ws + (size_t)NCHUNK * MPAD * 6 + (size_t)N_GT * 8);  // 192 KB

    // partG must be 0 each call (atomicMax accumulator; replay-safe)
    hipMemsetAsync(partG, 0, (size_t)N_GT * 8, stream);

    fused_kernel<<<dim3(NB, NCHUNK), 256, 0, stream>>>(bboxes, priors, part1iou,
                                                       part1idx, partG, force_n, M);
    rs_kernel<<<(N_GT + 255) / 256, 256, 0, stream>>>(partG, force_n);
    encode_kernel<<<(MPAD + 255) / 256, 256, 0, stream>>>(bboxes, labels, priors,
                                                          part1iou, part1idx,
                                                          force_n, out, M);
}